// Round 14
// baseline (278.654 us; speedup 1.0000x reference)
//
#include <hip/hip_runtime.h>
#include <math.h>

#define C 512
#define HW 4096
#define N 1024
#define NPIX 32768
#define MARGIN 2.0f

typedef short s16x8 __attribute__((ext_vector_type(8)));
typedef float f32x4 __attribute__((ext_vector_type(4)));

__device__ inline unsigned short f2bf(float f) {
    unsigned int u = __float_as_uint(f);
    return (unsigned short)((u + 0x7FFFu + ((u >> 16) & 1u)) >> 16);
}
__device__ inline float h2f(unsigned short u) {
    _Float16 h; __builtin_memcpy(&h, &u, 2); return (float)h;
}
__device__ inline unsigned short f2h(float f) {
    _Float16 h = (_Float16)f; unsigned short u; __builtin_memcpy(&u, &h, 2); return u;
}
__device__ inline unsigned int mono(float v) {
    unsigned int u = __float_as_uint(v);
    return (u & 0x80000000u) ? ~u : (u | 0x80000000u);
}
__device__ inline void gload_lds16(const void* gsrc, void* ldst) {
    __builtin_amdgcn_global_load_lds(
        (const __attribute__((address_space(1))) unsigned int*)gsrc,
        (__attribute__((address_space(3))) unsigned int*)ldst, 16, 0, 0);
}

// ---------- K0: row norms of centers (->cnorm) and clusters (->clnorm) ----------
__global__ __launch_bounds__(64) void k_norms(const float* __restrict__ centers,
                                              const float* __restrict__ clusters,
                                              float* __restrict__ cnorm,
                                              float* __restrict__ clnorm) {
    int r = blockIdx.x;
    const float* src = (r < N) ? (centers + (size_t)r * C) : (clusters + (size_t)(r - N) * C);
    int lane = threadIdx.x;
    float s = 0.f;
    for (int k = lane; k < C; k += 64) { float v = src[k]; s += v * v; }
    #pragma unroll
    for (int m = 1; m < 64; m <<= 1) s += __shfl_xor(s, m, 64);
    if (lane == 0) {
        float nrm = sqrtf(s);
        if (nrm < 1e-12f) nrm = 1e-12f;
        if (r < N) cnorm[r] = nrm; else clnorm[r - N] = nrm;
    }
}

// ---------- K1: M[i][j] = dot(centers[i],clusters[j]) / (cnorm[i]*clnorm[j]) ----------
__global__ __launch_bounds__(256) void k_gemmM(const float* __restrict__ centers,
                                               const float* __restrict__ clusters,
                                               const float* __restrict__ cnorm,
                                               const float* __restrict__ clnorm,
                                               float* __restrict__ M) {
    __shared__ float as[32][68];
    __shared__ float bs[32][68];
    int tid = threadIdx.x;
    int tx = tid & 15, ty = tid >> 4;
    int i0 = blockIdx.x * 64, j0 = blockIdx.y * 64;
    int lrow = tid >> 2, lkq = (tid & 3) * 8;
    float acc[4][4] = {};
    for (int kc = 0; kc < C; kc += 32) {
        float4 a0 = *(const float4*)(centers + (size_t)(i0 + lrow) * C + kc + lkq);
        float4 a1 = *(const float4*)(centers + (size_t)(i0 + lrow) * C + kc + lkq + 4);
        float4 b0 = *(const float4*)(clusters + (size_t)(j0 + lrow) * C + kc + lkq);
        float4 b1 = *(const float4*)(clusters + (size_t)(j0 + lrow) * C + kc + lkq + 4);
        __syncthreads();
        as[lkq+0][lrow]=a0.x; as[lkq+1][lrow]=a0.y; as[lkq+2][lrow]=a0.z; as[lkq+3][lrow]=a0.w;
        as[lkq+4][lrow]=a1.x; as[lkq+5][lrow]=a1.y; as[lkq+6][lrow]=a1.z; as[lkq+7][lrow]=a1.w;
        bs[lkq+0][lrow]=b0.x; bs[lkq+1][lrow]=b0.y; bs[lkq+2][lrow]=b0.z; bs[lkq+3][lrow]=b0.w;
        bs[lkq+4][lrow]=b1.x; bs[lkq+5][lrow]=b1.y; bs[lkq+6][lrow]=b1.z; bs[lkq+7][lrow]=b1.w;
        __syncthreads();
        #pragma unroll
        for (int k = 0; k < 32; k += 4) {
            float av[4][4], bv[4][4];
            #pragma unroll
            for (int kk = 0; kk < 4; ++kk) {
                float4 ta = *(const float4*)&as[k+kk][tx*4];
                float4 tb = *(const float4*)&bs[k+kk][ty*4];
                av[kk][0]=ta.x; av[kk][1]=ta.y; av[kk][2]=ta.z; av[kk][3]=ta.w;
                bv[kk][0]=tb.x; bv[kk][1]=tb.y; bv[kk][2]=tb.z; bv[kk][3]=tb.w;
            }
            #pragma unroll
            for (int kk = 0; kk < 4; ++kk)
                #pragma unroll
                for (int ii = 0; ii < 4; ++ii)
                    #pragma unroll
                    for (int jj = 0; jj < 4; ++jj)
                        acc[ii][jj] = fmaf(av[kk][ii], bv[kk][jj], acc[ii][jj]);
        }
    }
    float rci[4], rcj[4];
    #pragma unroll
    for (int ii = 0; ii < 4; ++ii) rci[ii] = cnorm[i0 + tx*4 + ii];
    #pragma unroll
    for (int jj = 0; jj < 4; ++jj) rcj[jj] = clnorm[j0 + ty*4 + jj];
    #pragma unroll
    for (int ii = 0; ii < 4; ++ii)
        #pragma unroll
        for (int jj = 0; jj < 4; ++jj)
            M[(size_t)(i0 + tx*4 + ii) * N + (j0 + ty*4 + jj)] = acc[ii][jj] / (rci[ii] * rcj[jj]);
}

// ---------- K2: per-row max + argmax (first-index tie-break) of M ----------
__global__ __launch_bounds__(256) void k_rowstat(const float* __restrict__ M,
                                                 float* __restrict__ rowmax,
                                                 int* __restrict__ rowarg) {
    __shared__ float sv[256];
    __shared__ int   sa[256];
    int i = blockIdx.x, tid = threadIdx.x;
    float bv = -INFINITY; int ba = 0;
    for (int j = tid; j < N; j += 256) {
        float v = M[(size_t)i * N + j];
        if (v > bv || (v == bv && j < ba)) { bv = v; ba = j; }
    }
    sv[tid] = bv; sa[tid] = ba;
    __syncthreads();
    for (int s = 128; s > 0; s >>= 1) {
        if (tid < s) {
            float v = sv[tid + s]; int a = sa[tid + s];
            if (v > sv[tid] || (v == sv[tid] && a < sa[tid])) { sv[tid] = v; sa[tid] = a; }
        }
        __syncthreads();
    }
    if (tid == 0) { rowmax[i] = sv[0]; rowarg[i] = sa[0]; }
}

// ---------- K3: transpose x[b][k][p] -> xT[b*4096+p][k], 128x128 tiles ----------
__global__ __launch_bounds__(256) void k_prepT(const float* __restrict__ x,
                                               float* __restrict__ xT) {
    __shared__ float t[128][129];
    int bidx = blockIdx.x;              // 8 b * 4 ktile * 32 ptile
    int pt = bidx & 31, kt = (bidx >> 5) & 3, b = bidx >> 7;
    int r0 = threadIdx.x >> 5, c4 = (threadIdx.x & 31) * 4;
    const float* src = x + ((size_t)b * C + kt * 128) * HW + pt * 128;
    #pragma unroll
    for (int rr = 0; rr < 16; ++rr) {
        int row = rr * 8 + r0;          // k within tile
        float4 v = *(const float4*)(src + (size_t)row * HW + c4);
        t[row][c4] = v.x; t[row][c4+1] = v.y; t[row][c4+2] = v.z; t[row][c4+3] = v.w;
    }
    __syncthreads();
    float* dst = xT + ((size_t)b * HW + pt * 128) * C + kt * 128;
    #pragma unroll
    for (int rr = 0; rr < 16; ++rr) {
        int row = rr * 8 + r0;          // pixel within tile
        float4 v = { t[c4][row], t[c4+1][row], t[c4+2][row], t[c4+3][row] };
        *(float4*)(dst + (size_t)row * C + c4) = v;
    }
}

// ---------- K4: centers -> bf16 MFMA B-fragments (fragment-linear) ----------
__global__ __launch_bounds__(64) void k_cenfrag(const float* __restrict__ centers,
                                                unsigned short* __restrict__ cenB) {
    int f = blockIdx.x;                 // nt*16 + kt
    int nt = f >> 4, kt = f & 15;
    int lane = threadIdx.x;
    int r = lane & 15, g = lane >> 4;
    const float* src = centers + (size_t)(nt * 16 + r) * C + kt * 32 + g * 4;
    float4 lo = *(const float4*)src;
    float4 hi = *(const float4*)(src + 16);
    union { unsigned short us[8]; uint4 q; } u;
    u.us[0]=f2bf(lo.x); u.us[1]=f2bf(lo.y); u.us[2]=f2bf(lo.z); u.us[3]=f2bf(lo.w);
    u.us[4]=f2bf(hi.x); u.us[5]=f2bf(hi.y); u.us[6]=f2bf(hi.z); u.us[7]=f2bf(hi.w);
    *(uint4*)(cenB + ((size_t)f * 64 + lane) * 8) = u.q;
}

// ---------- K5: FUSED — 4-buffer depth-2 pipeline, 1 barrier/tile ----------
__device__ inline void mfma_tile(const s16x8* a, const unsigned short* cenbuf, int lane,
                                 f32x4 gv, float* m4, unsigned int* kh) {
    const s16x8* bp = (const s16x8*)cenbuf + lane;
    f32x4 acc0 = {0.f,0.f,0.f,0.f}, acc1 = {0.f,0.f,0.f,0.f};
    #pragma unroll
    for (int kt = 0; kt < 16; kt += 2) {
        acc0 = __builtin_amdgcn_mfma_f32_16x16x32_bf16(a[kt],   bp[kt*64],     acc0, 0,0,0);
        acc1 = __builtin_amdgcn_mfma_f32_16x16x32_bf16(a[kt+1], bp[(kt+1)*64], acc1, 0,0,0);
    }
    float v0 = acc0[0]+acc1[0]+gv[0], v1 = acc0[1]+acc1[1]+gv[1];
    float v2 = acc0[2]+acc1[2]+gv[2], v3 = acc0[3]+acc1[3]+gv[3];
    m4[0] = fmaxf(m4[0], v0); m4[1] = fmaxf(m4[1], v1);
    m4[2] = fmaxf(m4[2], v2); m4[3] = fmaxf(m4[3], v3);
    kh[0] = (unsigned int)f2h(v0) | ((unsigned int)f2h(v1) << 16);
    kh[1] = (unsigned int)f2h(v2) | ((unsigned int)f2h(v3) << 16);
}

__global__ __launch_bounds__(256, 2) void k_fused(const float* __restrict__ xT,
                                                  const unsigned short* __restrict__ cenB,
                                                  const float* __restrict__ gumbel,
                                                  const float* __restrict__ centers,
                                                  int* __restrict__ idxb) {
    __shared__ unsigned short cen[4][8192];        // 4 x 16 KB cen tile rotation
    __shared__ unsigned long long pixkey[64];
    __shared__ unsigned int candlist[4][256];
    __shared__ int candcount[4];

    int tid = threadIdx.x;
    int lane = tid & 63, w = tid >> 6;             // 4 waves; wave = px-tile
    int r = lane & 15, g = lane >> 4;

    int p0 = blockIdx.x * 64;
    int b = p0 >> 12, hw0 = p0 & (HW - 1);

    if (tid < 64) pixkey[tid] = 0ull;
    if (tid < 4) candcount[tid] = 0;

    // ---- A fragments FIRST (fully consumed -> vmcnt clean before stages) ----
    s16x8 a[16];
    {
        const float* xrow = xT + (size_t)(p0 + w * 16 + r) * C;
        #pragma unroll
        for (int kt = 0; kt < 16; ++kt) {
            float4 lo = *(const float4*)(xrow + kt * 32 + g * 4);
            float4 hi = *(const float4*)(xrow + kt * 32 + 16 + g * 4);
            s16x8 t;
            t[0]=(short)f2bf(lo.x); t[1]=(short)f2bf(lo.y); t[2]=(short)f2bf(lo.z); t[3]=(short)f2bf(lo.w);
            t[4]=(short)f2bf(hi.x); t[5]=(short)f2bf(hi.y); t[6]=(short)f2bf(hi.z); t[7]=(short)f2bf(hi.w);
            a[kt] = t;
        }
    }
    const float* gpx = gumbel + (size_t)b * N * HW + hw0 + w * 16 + g * 4;
    f32x4 gvp[4];

    #define STAGE_CEN(T, BUF) { \
        const char* s_ = (const char*)cenB + (size_t)(T) * 16384 + w * 4096 + lane * 16; \
        char* d_ = (char*)&cen[BUF][0] + w * 4096; \
        gload_lds16(s_, d_); gload_lds16(s_ + 1024, d_ + 1024); \
        gload_lds16(s_ + 2048, d_ + 2048); gload_lds16(s_ + 3072, d_ + 3072); }
    #define LOAD_GV(T, SLOT) gvp[SLOT] = *(const f32x4*)(gpx + (size_t)((T) * 16 + r) * HW);

    // ---- prologue: drain A-frag loads, then stage tiles 0,1,2 ----
    asm volatile("s_waitcnt vmcnt(0)" ::: "memory");
    __builtin_amdgcn_sched_barrier(0);
    STAGE_CEN(0, 0); LOAD_GV(0, 0);
    STAGE_CEN(1, 1); LOAD_GV(1, 1);
    STAGE_CEN(2, 2); LOAD_GV(2, 2);
    __builtin_amdgcn_sched_barrier(0);
    asm volatile("s_waitcnt vmcnt(10)" ::: "memory");   // stage(0)+gv(0) done
    __builtin_amdgcn_s_barrier();
    __builtin_amdgcn_sched_barrier(0);

    float m4[4] = {-INFINITY, -INFINITY, -INFINITY, -INFINITY};

    #define SCAN_CHUNK(TCB, KH) { \
        _Pragma("unroll") \
        for (int s2 = 1; s2 < 16; s2 <<= 1) { \
            _Pragma("unroll") \
            for (int j = 0; j < 4; ++j) m4[j] = fmaxf(m4[j], __shfl_xor(m4[j], s2, 64)); \
        } \
        float thr[4]; \
        _Pragma("unroll") \
        for (int j = 0; j < 4; ++j) thr[j] = m4[j] - MARGIN; \
        _Pragma("unroll") \
        for (int s = 0; s < 8; ++s) { \
            int nn = (((TCB) * 8 + s) << 4) + r; \
            _Pragma("unroll") \
            for (int j2 = 0; j2 < 2; ++j2) { \
                unsigned int pk = (KH)[s * 2 + j2]; \
                float lo = h2f((unsigned short)(pk & 0xFFFFu)); \
                float hi = h2f((unsigned short)(pk >> 16)); \
                if (lo >= thr[j2 * 2]) { \
                    int pos = atomicAdd(&candcount[w], 1); \
                    if (pos < 256) candlist[w][pos] = \
                        (unsigned int)nn | ((unsigned int)(w * 16 + g * 4 + j2 * 2) << 10); \
                } \
                if (hi >= thr[j2 * 2 + 1]) { \
                    int pos = atomicAdd(&candcount[w], 1); \
                    if (pos < 256) candlist[w][pos] = \
                        (unsigned int)nn | ((unsigned int)(w * 16 + g * 4 + j2 * 2 + 1) << 10); \
                } \
            } \
        } }

    // ---- main: 7 full chunks (t = 0..55), steady-state pipeline ----
    for (int tc = 0; tc < 7; ++tc) {
        unsigned int keepH[16];
        #pragma unroll
        for (int s = 0; s < 8; ++s) {
            int t = tc * 8 + s;
            // issue stage(t+3) at iter top (max flight time); t+3 <= 58 always here
            STAGE_CEN(t + 3, (s + 3) & 3);
            LOAD_GV(t + 3, (s + 3) & 3);
            __builtin_amdgcn_sched_barrier(0);
            mfma_tile(a, &cen[s & 3][0], lane, gvp[s & 3], m4, &keepH[s * 2]);
            __builtin_amdgcn_sched_barrier(0);
            asm volatile("s_waitcnt vmcnt(10) lgkmcnt(0)" ::: "memory");
            __builtin_amdgcn_s_barrier();
            __builtin_amdgcn_sched_barrier(0);
        }
        SCAN_CHUNK(tc, keepH);
    }
    // ---- epilogue chunk: t = 56..63, static tail waits ----
    {
        unsigned int keepH[16];
        #pragma unroll
        for (int s = 0; s < 8; ++s) {
            int t = 56 + s;
            if (s <= 4) {                           // t+3 = 59..63
                STAGE_CEN(t + 3, (s + 3) & 3);
                LOAD_GV(t + 3, (s + 3) & 3);
            }
            __builtin_amdgcn_sched_barrier(0);
            mfma_tile(a, &cen[s & 3][0], lane, gvp[s & 3], m4, &keepH[s * 2]);
            __builtin_amdgcn_sched_barrier(0);
            if (s <= 4)      { asm volatile("s_waitcnt vmcnt(10) lgkmcnt(0)" ::: "memory"); }
            else if (s == 5) { asm volatile("s_waitcnt vmcnt(5) lgkmcnt(0)" ::: "memory"); }
            else if (s == 6) { asm volatile("s_waitcnt vmcnt(0) lgkmcnt(0)" ::: "memory"); }
            if (s < 7) { __builtin_amdgcn_s_barrier(); }
            __builtin_amdgcn_sched_barrier(0);
        }
        SCAN_CHUNK(7, keepH);
    }
    #undef STAGE_CEN
    #undef LOAD_GV
    #undef SCAN_CHUNK

    // ---- exact fp32 refine: 4 candidates/wave in parallel, x from xT (L2-hot) ----
    int cc = candcount[w]; if (cc > 256) cc = 256;
    int sl = lane & 15, cg = lane >> 4;
    for (int t0 = 0; t0 < cc; t0 += 4) {
        int c = t0 + cg;
        bool valid = c < cc;
        unsigned int e = candlist[w][valid ? c : 0];
        int n = (int)(e & 1023u), pl = (int)(e >> 10);
        const float* xr = xT + (size_t)(p0 + pl) * C;
        const float* cenr = centers + (size_t)n * C;
        float s = 0.f;
        #pragma unroll
        for (int m = 0; m < 8; ++m) {
            int G = sl + (m << 4);
            float4 xv = *(const float4*)(xr + (G << 2));
            float4 cv = *(const float4*)(cenr + (G << 2));
            s = fmaf(xv.x, cv.x, s); s = fmaf(xv.y, cv.y, s);
            s = fmaf(xv.z, cv.z, s); s = fmaf(xv.w, cv.w, s);
        }
        #pragma unroll
        for (int s2 = 1; s2 < 16; s2 <<= 1) s += __shfl_xor(s, s2, 64);
        if (valid && sl == 0) {
            float val = s + gumbel[((size_t)b * N + n) * HW + hw0 + pl];
            unsigned long long key = ((unsigned long long)mono(val) << 32) | (unsigned int)(1023 - n);
            atomicMax(&pixkey[pl], key);
        }
    }
    __syncthreads();
    if (tid < 64) idxb[p0 + tid] = 1023 - (int)(unsigned int)(pixkey[tid] & 0xFFFFFFFFull);
}

// ---------- K6: preds (as float) + per-block loss partial sums ----------
__global__ __launch_bounds__(256) void k_preds(const int* __restrict__ idxb,
                                               const float* __restrict__ rowmax,
                                               const int* __restrict__ rowarg,
                                               float* __restrict__ preds_out,
                                               float* __restrict__ partial) {
    __shared__ float sv[256];
    int gid = blockIdx.x * 256 + threadIdx.x;
    int i = idxb[gid];
    preds_out[gid] = (float)rowarg[i];
    sv[threadIdx.x] = rowmax[i];
    __syncthreads();
    for (int s = 128; s > 0; s >>= 1) {
        if (threadIdx.x < s) sv[threadIdx.x] += sv[threadIdx.x + s];
        __syncthreads();
    }
    if (threadIdx.x == 0) partial[blockIdx.x] = sv[0];
}

// ---------- K7: gather rows of src by idx, 256-px tiles, 1KB write granules ----------
__global__ __launch_bounds__(256) void k_gather(const float* __restrict__ src, int ncols,
                                                const int* __restrict__ idx,
                                                float* __restrict__ dst) {
    __shared__ float rows[256][65];
    int tile = blockIdx.x;              // 128 tiles of 256 px
    int col0 = blockIdx.y * 64;
    int tid = threadIdx.x;
    int lane = tid & 63, w = tid >> 6;
    int p0 = tile * 256;
    int b = p0 >> 12, hw0 = p0 & (HW - 1);
    for (int r8 = 0; r8 < 64; ++r8) {
        int rrow = w * 64 + r8;
        int row = idx[p0 + rrow];
        rows[rrow][lane] = src[(size_t)row * ncols + col0 + lane];
    }
    __syncthreads();
    #pragma unroll
    for (int jj = 0; jj < 16; ++jj) {
        int j = col0 + w * 16 + jj;
        #pragma unroll
        for (int q = 0; q < 4; ++q)
            dst[((size_t)b * ncols + j) * HW + hw0 + q * 64 + lane] = rows[q * 64 + lane][w * 16 + jj];
    }
}

// ---------- K8: finalize loss ----------
__global__ __launch_bounds__(128) void k_loss(const float* __restrict__ partial,
                                              float* __restrict__ out) {
    __shared__ float sv[128];
    sv[threadIdx.x] = partial[threadIdx.x];
    __syncthreads();
    for (int s = 64; s > 0; s >>= 1) {
        if (threadIdx.x < s) sv[threadIdx.x] += sv[threadIdx.x + s];
        __syncthreads();
    }
    if (threadIdx.x == 0) out[0] = -(sv[0] / 32768.0f);
}

extern "C" void kernel_launch(void* const* d_in, const int* in_sizes, int n_in,
                              void* d_out, int out_size, void* d_ws, size_t ws_size,
                              hipStream_t stream) {
    const float* x        = (const float*)d_in[0];
    const float* centers  = (const float*)d_in[1];
    const float* clusters = (const float*)d_in[2];
    const float* gumbel   = (const float*)d_in[3];
    float* out = (float*)d_out;

    char* w = (char*)d_ws;
    int*   idxb    = (int*)w;                                  // 128 KB
    float* cnorm   = (float*)(w + 131072);                     // 4 KB
    float* clnorm  = cnorm + 1024;
    float* rowmax  = clnorm + 1024;
    int*   rowarg  = (int*)(rowmax + 1024);
    float* partial = (float*)(rowarg + 1024);
    float* M       = (float*)(w + 262144);                     // 4 MB
    unsigned short* cenB = (unsigned short*)(w + 4456448);     // 1 MB

    float* out_loss  = out;
    float* out_preds = out + 1;
    float* out_ip    = out + 1 + 32768;
    float* out_zq    = out + 1 + 32768 + (size_t)N * NPIX;

    // xT scratch lives in the zq output region (dead until the final gather)
    float* xT = out_zq;                                        // 32768 x 512 fp32, exact fit

    k_norms  <<<2048, 64, 0, stream>>>(centers, clusters, cnorm, clnorm);
    k_gemmM  <<<dim3(16, 16), 256, 0, stream>>>(centers, clusters, cnorm, clnorm, M);
    k_rowstat<<<1024, 256, 0, stream>>>(M, rowmax, rowarg);
    k_cenfrag<<<1024, 64, 0, stream>>>(centers, cenB);
    k_prepT  <<<1024, 256, 0, stream>>>(x, xT);
    k_fused  <<<512, 256, 0, stream>>>(xT, cenB, gumbel, centers, idxb);
    k_preds  <<<128, 256, 0, stream>>>(idxb, rowmax, rowarg, out_preds, partial);
    k_gather <<<dim3(128, 16), 256, 0, stream>>>(M, N, idxb, out_ip);
    k_gather <<<dim3(128, 8),  256, 0, stream>>>(centers, C, idxb, out_zq);
    k_loss   <<<1, 128, 0, stream>>>(partial, out_loss);
}